// Round 5
// baseline (2441.956 us; speedup 1.0000x reference)
//
#include <hip/hip_runtime.h>
#include <hip/hip_bf16.h>
#include <hip/hip_fp16.h>

typedef _Float16 half8 __attribute__((ext_vector_type(8)));
typedef _Float16 half4v __attribute__((ext_vector_type(4)));
typedef float f4 __attribute__((ext_vector_type(4)));
typedef float f16v __attribute__((ext_vector_type(16)));
typedef short short8 __attribute__((ext_vector_type(8)));
typedef int i4 __attribute__((ext_vector_type(4)));

#define P_SZ 4096
#define CH 256      // hidden (qk) channels
#define CIN 512     // input channels
#define CV 512      // value channels
#define KVB 32      // keys per tile

__device__ __forceinline__ unsigned short f2bf(float f) {
  unsigned u = __float_as_uint(f);
  unsigned r = u + 0x7fffu + ((u >> 16) & 1u);
  return (unsigned short)(r >> 16);
}
__device__ __forceinline__ float bf2f(unsigned short h) {
  return __uint_as_float(((unsigned)h) << 16);
}

__device__ __forceinline__ void gload16(const void* g, void* l) {
  __builtin_amdgcn_global_load_lds(
      (const __attribute__((address_space(1))) unsigned int*)g,
      (__attribute__((address_space(3))) unsigned int*)l, 16, 0, 0);
}

// ---------------- V convert: fp32 [b][c][p] -> fp16 chunk-major tiles ----------------
// Vt layout: [b][ktile=128][kh=4][512 ch][8 f16 keys]
__global__ __launch_bounds__(256) void vconv_kernel(const float* __restrict__ in,
                                                    _Float16* __restrict__ outv) {
  const size_t i = (size_t)blockIdx.x * 256 + threadIdx.x;
  const f4 x = ((const f4*)in)[i];
  half4v h;
  h[0] = (_Float16)x[0]; h[1] = (_Float16)x[1];
  h[2] = (_Float16)x[2]; h[3] = (_Float16)x[3];
  const int pq = (int)(i & 1023);
  const int ch = (int)((i >> 10) & 511);
  const int b  = (int)(i >> 19);
  const int p0 = pq * 4;
  const size_t idx = (size_t)b * 2097152 + (size_t)(p0 >> 5) * 16384
                   + (size_t)((p0 >> 3) & 3) * 4096 + ch * 8 + (p0 & 7);
  *(half4v*)(outv + idx) = h;
}

// ---------------- Projection (split-bf16, ~fp32 accurate), fp16 out ----------------
// Q: natural [b][p][256].  K: chunk-major [b][ktile=128][32 chunks c=ch>>3][32 key][8 f16]
__global__ __launch_bounds__(512) void proj_kernel(
    const float* __restrict__ Xq, const float* __restrict__ Wq, const float* __restrict__ bq,
    const float* __restrict__ Xk, const float* __restrict__ Wk, const float* __restrict__ bk,
    _Float16* __restrict__ Qout, _Float16* __restrict__ Kout) {
  const int which = blockIdx.z;
  const float* __restrict__ X = which ? Xk : Xq;
  const float* __restrict__ W = which ? Wk : Wq;
  const float* __restrict__ bias = which ? bk : bq;
  _Float16* __restrict__ out = which ? Kout : Qout;

  const int b = blockIdx.y;
  const int p0 = blockIdx.x * 64;
  const int tid = threadIdx.x;
  const int w = tid >> 6, l = tid & 63;
  const int wp = w >> 2, wo = w & 3;
  const int lr = l & 15, lg = l >> 4;

  const float* __restrict__ Xb = X + (size_t)b * CIN * P_SZ;

  f4 acc[2][4];
  #pragma unroll
  for (int m = 0; m < 2; ++m)
    #pragma unroll
    for (int n = 0; n < 4; ++n) acc[m][n] = (f4){0.f, 0.f, 0.f, 0.f};

  const int prow0 = p0 + wp * 32 + lr;

  #pragma unroll 1
  for (int kc = 0; kc < CIN; kc += 32) {
    short8 ah[2], al[2];
    #pragma unroll
    for (int m = 0; m < 2; ++m) {
      const float* xp = Xb + (size_t)(kc + lg * 8) * P_SZ + (prow0 + m * 16);
      #pragma unroll
      for (int i = 0; i < 8; ++i) {
        float xv = xp[(size_t)i * P_SZ];
        unsigned short h = f2bf(xv);
        ah[m][i] = (short)h;
        al[m][i] = (short)f2bf(xv - bf2f(h));
      }
    }
    short8 bh[4], bl[4];
    #pragma unroll
    for (int n = 0; n < 4; ++n) {
      const float* wr = W + (size_t)(wo * 64 + n * 16 + lr) * CIN + kc + lg * 8;
      #pragma unroll
      for (int i = 0; i < 8; ++i) {
        float wv = wr[i];
        unsigned short h = f2bf(wv);
        bh[n][i] = (short)h;
        bl[n][i] = (short)f2bf(wv - bf2f(h));
      }
    }
    #pragma unroll
    for (int m = 0; m < 2; ++m)
      #pragma unroll
      for (int n = 0; n < 4; ++n) {
        acc[m][n] = __builtin_amdgcn_mfma_f32_16x16x32_bf16(ah[m], bh[n], acc[m][n], 0, 0, 0);
        acc[m][n] = __builtin_amdgcn_mfma_f32_16x16x32_bf16(ah[m], bl[n], acc[m][n], 0, 0, 0);
        acc[m][n] = __builtin_amdgcn_mfma_f32_16x16x32_bf16(al[m], bh[n], acc[m][n], 0, 0, 0);
      }
  }

  #pragma unroll
  for (int n = 0; n < 4; ++n) {
    const int o = wo * 64 + n * 16 + lr;
    const float bv = bias[o];
    #pragma unroll
    for (int m = 0; m < 2; ++m) {
      #pragma unroll
      for (int j = 0; j < 4; ++j) {
        const int p = p0 + wp * 32 + m * 16 + lg * 4 + j;
        const _Float16 val = (_Float16)(acc[m][n][j] + bv);
        if (which == 0) {
          out[((size_t)b * P_SZ + p) * CH + o] = val;
        } else {
          out[(size_t)b * 1048576 + (size_t)(p >> 5) * 8192
              + (size_t)(o >> 3) * 256 + (p & 31) * 8 + (o & 7)] = val;
        }
      }
    }
  }
}

// ---------------- Fused flash attention: swapped QK^T, in-register softmax ----------------
// 8 waves; wave w owns q rows qt*256 + w*32 .. +32, ALL 512 out channels.
// K/V chunk-major in LDS (3-buffer, 2-deep global_load_lds pipeline, 1 barrier/iter).
// S^T = mfma_32x32x16(K, Q) -> lane(l31,hi) holds S[key=(r&3)+8*(r>>2)+4*hi][q=l31].
// P-fragment redistribution: cross-half copies via shfl_xor(32), then select by
// DESTINATION half (round-4 bug: pre-select by source half delivered wrong keys).
template <int NSEG, bool DIRECT>
__global__ __launch_bounds__(512) void attn_kernel(
    const _Float16* __restrict__ Qg, const _Float16* __restrict__ Kt,
    const _Float16* __restrict__ Vt, float* __restrict__ Opart,
    float* __restrict__ Mp, float* __restrict__ Lp, float* __restrict__ Og) {
  __shared__ char K_l[3][16384];
  __shared__ char V_l[3][32768];

  constexpr int nt = (P_SZ / NSEG) / KVB;
  int b, qt, seg;
  if (NSEG == 4) {
    const int xcd = blockIdx.x & 7, i = blockIdx.x >> 3;
    const int g = xcd * 2 + (i & 1);
    qt = i >> 1; b = g >> 2; seg = g & 3;
  } else {
    b = blockIdx.x & 3; qt = blockIdx.x >> 2; seg = 0;
  }

  const int tid = threadIdx.x;
  const int w = tid >> 6, l = tid & 63;
  const int hi = l >> 5, l31 = l & 31;

  const char* Kb = (const char*)Kt + (size_t)b * 2097152 + (size_t)seg * nt * 16384;
  const char* Vb = (const char*)Vt + (size_t)b * 4194304 + (size_t)seg * nt * 32768;

#define STAGE(BUF, T) do { \
    const char* ksrc = Kb + (size_t)(T) * 16384; \
    const char* vsrc = Vb + (size_t)(T) * 32768; \
    gload16(ksrc + tid * 16,         &K_l[BUF][w * 1024]); \
    gload16(ksrc + 8192 + tid * 16,  &K_l[BUF][8192 + w * 1024]); \
    gload16(vsrc + tid * 16,         &V_l[BUF][w * 1024]); \
    gload16(vsrc + 8192 + tid * 16,  &V_l[BUF][8192 + w * 1024]); \
    gload16(vsrc + 16384 + tid * 16, &V_l[BUF][16384 + w * 1024]); \
    gload16(vsrc + 24576 + tid * 16, &V_l[BUF][24576 + w * 1024]); \
  } while (0)

  // Q fragments: B-operand [q=lane&31][ch chunks], natural global layout
  half8 qf[16];
  {
    const char* qrow = (const char*)Qg + ((size_t)b * P_SZ + qt * 256 + w * 32 + l31) * 512;
    #pragma unroll
    for (int m = 0; m < 16; ++m) qf[m] = *(const half8*)(qrow + m * 32 + hi * 16);
  }

  f16v acc[16];
  #pragma unroll
  for (int n = 0; n < 16; ++n)
    acc[n] = (f16v){0,0,0,0, 0,0,0,0, 0,0,0,0, 0,0,0,0};

  float m_run = -1e30f, lsum = 0.f;
  const int kread = hi * 512 + l31 * 16;    // + m*1024
  const int vread = hi * 8192 + l31 * 16;   // + ks*16384 + n*512

  STAGE(0, 0); STAGE(1, 1);
  asm volatile("s_waitcnt vmcnt(6)" ::: "memory");
  asm volatile("s_barrier" ::: "memory");
  __builtin_amdgcn_sched_barrier(0);

  int bufc = 0;
  #pragma unroll 1
  for (int t = 0; t < nt; ++t) {
    // ---- swapped QK^T: S^T[key][q] ----
    const char* kb = &K_l[bufc][0] + kread;
    f16v s = (f16v){0,0,0,0, 0,0,0,0, 0,0,0,0, 0,0,0,0};
    __builtin_amdgcn_s_setprio(1);
    #pragma unroll
    for (int m = 0; m < 16; ++m) {
      half8 kf = *(const half8*)(kb + m * 1024);
      s = __builtin_amdgcn_mfma_f32_32x32x16_f16(kf, qf[m], s, 0, 0, 0);
    }
    __builtin_amdgcn_s_setprio(0);

    // ---- in-register online softmax over 32 keys (per q=l31) ----
    float x0 = fmaxf(s[0], s[8]),  x1 = fmaxf(s[1], s[9]);
    float x2 = fmaxf(s[2], s[10]), x3 = fmaxf(s[3], s[11]);
    float x4 = fmaxf(s[4], s[12]), x5 = fmaxf(s[5], s[13]);
    float x6 = fmaxf(s[6], s[14]), x7 = fmaxf(s[7], s[15]);
    x0 = fmaxf(x0, x4); x1 = fmaxf(x1, x5); x2 = fmaxf(x2, x6); x3 = fmaxf(x3, x7);
    float pm = fmaxf(fmaxf(x0, x1), fmaxf(x2, x3));
    pm = fmaxf(pm, __shfl_xor(pm, 32));
    if (__any(pm > m_run + 10.f)) {          // rare rescale (defer-max, T13)
      const float mnew = fmaxf(m_run, pm);
      const float al = __expf(m_run - mnew);
      const int alb = __float_as_int(al);
      #pragma unroll
      for (int r = 0; r < 16; ++r) {
        const int cr = (r & 3) + 8 * (r >> 2);
        const float ar = __int_as_float(
            __builtin_amdgcn_ds_bpermute(cr * 4 + hi * 16, alb));
        #pragma unroll
        for (int n = 0; n < 16; ++n) acc[n][r] *= ar;
      }
      lsum *= al;
      m_run = mnew;
    }
    float p[16], psum;
    #pragma unroll
    for (int r = 0; r < 16; ++r) p[r] = __expf(s[r] - m_run);
    {
      float a0 = (p[0] + p[1]) + (p[2] + p[3]);
      float a1 = (p[4] + p[5]) + (p[6] + p[7]);
      float a2 = (p[8] + p[9]) + (p[10] + p[11]);
      float a3 = (p[12] + p[13]) + (p[14] + p[15]);
      psum = (a0 + a1) + (a2 + a3);
      psum += __shfl_xor(psum, 32);
    }
    lsum += psum;

    // ---- P -> fp16 A-fragments ----
    // lane(l31,hi) holds P for keys: c0:(0,1)+4hi c1:(2,3)+4hi c2:(8,9)+4hi
    // c3:(10,11)+4hi c4:(16,17)+4hi c5:(18,19)+4hi c6:(24,25)+4hi c7:(26,27)+4hi.
    // pa0 needs keys [8hi..8hi+7], pa1 keys [16+8hi..23+8hi]; cross-half copy
    // (shfl_xor 32) then select by DESTINATION hi.
    const int c0 = __builtin_bit_cast(int, __builtin_amdgcn_cvt_pkrtz(p[0], p[1]));
    const int c1 = __builtin_bit_cast(int, __builtin_amdgcn_cvt_pkrtz(p[2], p[3]));
    const int c2 = __builtin_bit_cast(int, __builtin_amdgcn_cvt_pkrtz(p[4], p[5]));
    const int c3 = __builtin_bit_cast(int, __builtin_amdgcn_cvt_pkrtz(p[6], p[7]));
    const int c4 = __builtin_bit_cast(int, __builtin_amdgcn_cvt_pkrtz(p[8], p[9]));
    const int c5 = __builtin_bit_cast(int, __builtin_amdgcn_cvt_pkrtz(p[10], p[11]));
    const int c6 = __builtin_bit_cast(int, __builtin_amdgcn_cvt_pkrtz(p[12], p[13]));
    const int c7 = __builtin_bit_cast(int, __builtin_amdgcn_cvt_pkrtz(p[14], p[15]));
    const int c0x = __shfl_xor(c0, 32), c1x = __shfl_xor(c1, 32);
    const int c2x = __shfl_xor(c2, 32), c3x = __shfl_xor(c3, 32);
    const int c4x = __shfl_xor(c4, 32), c5x = __shfl_xor(c5, 32);
    const int c6x = __shfl_xor(c6, 32), c7x = __shfl_xor(c7, 32);
    i4 w0v, w1v;
    w0v[0] = hi ? c2x : c0;  w0v[1] = hi ? c3x : c1;
    w0v[2] = hi ? c2  : c0x; w0v[3] = hi ? c3  : c1x;
    w1v[0] = hi ? c6x : c4;  w1v[1] = hi ? c7x : c5;
    w1v[2] = hi ? c6  : c4x; w1v[3] = hi ? c7  : c5x;
    const half8 pa0 = __builtin_bit_cast(half8, w0v);
    const half8 pa1 = __builtin_bit_cast(half8, w1v);

    // ---- issue stage t+2 (2-deep pipeline) ----
    const int bufs = bufc == 0 ? 2 : bufc - 1;   // (bufc+2)%3
    if (t + 2 < nt) STAGE(bufs, t + 2);

    // ---- PV: acc[q][ch] += P * V ----
    const char* vb = &V_l[bufc][0] + vread;
    __builtin_amdgcn_s_setprio(1);
    #pragma unroll
    for (int n = 0; n < 16; ++n) {
      half8 v0 = *(const half8*)(vb + n * 512);
      acc[n] = __builtin_amdgcn_mfma_f32_32x32x16_f16(pa0, v0, acc[n], 0, 0, 0);
      half8 v1 = *(const half8*)(vb + 16384 + n * 512);
      acc[n] = __builtin_amdgcn_mfma_f32_32x32x16_f16(pa1, v1, acc[n], 0, 0, 0);
    }
    __builtin_amdgcn_s_setprio(0);

    if (t + 2 < nt) { asm volatile("s_waitcnt vmcnt(6)" ::: "memory"); }
    else            { asm volatile("s_waitcnt vmcnt(0)" ::: "memory"); }
    asm volatile("s_barrier" ::: "memory");
    __builtin_amdgcn_sched_barrier(0);
    bufc = bufc == 2 ? 0 : bufc + 1;
  }
#undef STAGE

  const int qg0 = qt * 256 + w * 32;
  if (!DIRECT) {
    float* Ob = Opart + (((size_t)seg * 4 + b) * P_SZ + qg0) * 512 + l31;
    #pragma unroll
    for (int n = 0; n < 16; ++n) {
      #pragma unroll
      for (int r = 0; r < 16; ++r) {
        const int q = (r & 3) + 8 * (r >> 2) + 4 * hi;
        Ob[(size_t)q * 512 + n * 32] = acc[n][r];
      }
    }
    if (l < 32) {
      const size_t mi = ((size_t)seg * 4 + b) * P_SZ + qg0 + l31;
      Mp[mi] = m_run; Lp[mi] = lsum;
    }
  } else {
    float linv[16];
    const int lb = __float_as_int(lsum);
    #pragma unroll
    for (int r = 0; r < 16; ++r) {
      const int cr = (r & 3) + 8 * (r >> 2);
      const float lq = __int_as_float(__builtin_amdgcn_ds_bpermute(cr * 4 + hi * 16, lb));
      linv[r] = 1.f / lq;
    }
    #pragma unroll
    for (int n = 0; n < 16; ++n) {
      #pragma unroll
      for (int r = 0; r < 16; ++r) {
        const int q = (r & 3) + 8 * (r >> 2) + 4 * hi;
        Og[((size_t)b * CV + n * 32 + l31) * P_SZ + qg0 + q] = acc[n][r] * linv[r];
      }
    }
  }
}

// ---------------- Combine: merge kv-segments, normalize, transpose [q][ch]->[ch][q] ----
template <int NSEG>
__global__ __launch_bounds__(256) void combine_kernel(
    const float* __restrict__ Opart, const float* __restrict__ Mp,
    const float* __restrict__ Lp, float* __restrict__ Og) {
  __shared__ float T[64][65];
  const int bx = blockIdx.x;
  const int ct = bx & 7, qt = (bx >> 3) & 63, b = bx >> 9;
  const int tid = threadIdx.x;
  {
    const int qi = tid >> 2, cj = tid & 3;
    const int q = qt * 64 + qi;
    const size_t mibase = (size_t)b * P_SZ + q;
    float M = -1e30f;
    #pragma unroll
    for (int s = 0; s < NSEG; ++s) M = fmaxf(M, Mp[(size_t)s * 4 * P_SZ + mibase]);
    float L = 0.f;
    f4 o0 = {0,0,0,0}, o1 = {0,0,0,0}, o2 = {0,0,0,0}, o3 = {0,0,0,0};
    #pragma unroll
    for (int s = 0; s < NSEG; ++s) {
      const float wgt = __expf(Mp[(size_t)s * 4 * P_SZ + mibase] - M);
      L += wgt * Lp[(size_t)s * 4 * P_SZ + mibase];
      const float* src = Opart + (((size_t)s * 4 + b) * P_SZ + q) * 512 + ct * 64 + cj * 16;
      o0 += wgt * ((const f4*)src)[0];
      o1 += wgt * ((const f4*)src)[1];
      o2 += wgt * ((const f4*)src)[2];
      o3 += wgt * ((const f4*)src)[3];
    }
    const float inv = 1.f / L;
    #pragma unroll
    for (int e = 0; e < 4; ++e) {
      T[qi][cj * 16 + e]      = o0[e] * inv;
      T[qi][cj * 16 + 4 + e]  = o1[e] * inv;
      T[qi][cj * 16 + 8 + e]  = o2[e] * inv;
      T[qi][cj * 16 + 12 + e] = o3[e] * inv;
    }
  }
  __syncthreads();
  const int ci = tid >> 2, qj = tid & 3;
  #pragma unroll
  for (int i = 0; i < 4; ++i) {
    f4 v;
    #pragma unroll
    for (int e = 0; e < 4; ++e) v[e] = T[qj * 16 + i * 4 + e][ci];
    *(f4*)&Og[((size_t)b * CV + ct * 64 + ci) * P_SZ + qt * 64 + qj * 16 + i * 4] = v;
  }
}

extern "C" void kernel_launch(void* const* d_in, const int* in_sizes, int n_in,
                              void* d_out, int out_size, void* d_ws, size_t ws_size,
                              hipStream_t stream) {
  const float* x  = (const float*)d_in[0];
  const float* f  = (const float*)d_in[1];
  const float* Wq = (const float*)d_in[2];
  const float* bq = (const float*)d_in[3];
  const float* Wk = (const float*)d_in[4];
  const float* bk = (const float*)d_in[5];
  float* out = (float*)d_out;

  char* ws = (char*)d_ws;
  _Float16* Qf = (_Float16*)ws;                                   // 8 MB natural
  _Float16* Kf = (_Float16*)(ws + ((size_t)8 << 20));             // 8 MB chunk-tiled
  _Float16* Vf = (_Float16*)(ws + ((size_t)16 << 20));            // 16 MB chunk-tiled
  float* Mp    = (float*)(ws + ((size_t)32 << 20));               // 256 KB
  float* Lp    = (float*)(ws + ((size_t)32 << 20) + 262144);      // 256 KB
  float* Opart = (float*)(ws + ((size_t)33 << 20));               // nseg*32 MB

  vconv_kernel<<<dim3(8192), dim3(256), 0, stream>>>(f, Vf);
  proj_kernel<<<dim3(64, 4, 2), dim3(512), 0, stream>>>(x, Wq, bq, f, Wk, bk, Qf, Kf);

  const size_t need4 = ((size_t)33 << 20) + ((size_t)128 << 20);
  const size_t need1 = ((size_t)33 << 20) + ((size_t)32 << 20);
  if (ws_size >= need4) {
    attn_kernel<4, false><<<dim3(256), dim3(512), 0, stream>>>(Qf, Kf, Vf, Opart, Mp, Lp, nullptr);
    combine_kernel<4><<<dim3(2048), dim3(256), 0, stream>>>(Opart, Mp, Lp, out);
  } else if (ws_size >= need1) {
    attn_kernel<1, false><<<dim3(64), dim3(512), 0, stream>>>(Qf, Kf, Vf, Opart, Mp, Lp, nullptr);
    combine_kernel<1><<<dim3(2048), dim3(256), 0, stream>>>(Opart, Mp, Lp, out);
  } else {
    attn_kernel<1, true><<<dim3(64), dim3(512), 0, stream>>>(Qf, Kf, Vf, nullptr, nullptr, nullptr, out);
  }
}

// Round 6
// 261.533 us; speedup vs baseline: 9.3371x; 9.3371x over previous
//
#include <hip/hip_runtime.h>
#include <hip/hip_bf16.h>
#include <hip/hip_fp16.h>

typedef _Float16 half8 __attribute__((ext_vector_type(8)));
typedef _Float16 half4v __attribute__((ext_vector_type(4)));
typedef float f4 __attribute__((ext_vector_type(4)));
typedef float f16v __attribute__((ext_vector_type(16)));
typedef short short8 __attribute__((ext_vector_type(8)));
typedef int i4 __attribute__((ext_vector_type(4)));

#define P_SZ 4096
#define CH 256      // hidden (qk) channels
#define CIN 512     // input channels
#define CV 512      // value channels
#define KVB 32      // keys per tile

__device__ __forceinline__ unsigned short f2bf(float f) {
  unsigned u = __float_as_uint(f);
  unsigned r = u + 0x7fffu + ((u >> 16) & 1u);
  return (unsigned short)(r >> 16);
}
__device__ __forceinline__ float bf2f(unsigned short h) {
  return __uint_as_float(((unsigned)h) << 16);
}

__device__ __forceinline__ void gload16(const void* g, void* l) {
  __builtin_amdgcn_global_load_lds(
      (const __attribute__((address_space(1))) unsigned int*)g,
      (__attribute__((address_space(3))) unsigned int*)l, 16, 0, 0);
}

// ---------------- V convert: fp32 [b][c][p] -> fp16 chunk-major tiles ----------------
// Vt layout: [b][ktile=128][kh=4][512 ch][8 f16 keys]
__global__ __launch_bounds__(256) void vconv_kernel(const float* __restrict__ in,
                                                    _Float16* __restrict__ outv) {
  const size_t i = (size_t)blockIdx.x * 256 + threadIdx.x;
  const f4 x = ((const f4*)in)[i];
  half4v h;
  h[0] = (_Float16)x[0]; h[1] = (_Float16)x[1];
  h[2] = (_Float16)x[2]; h[3] = (_Float16)x[3];
  const int pq = (int)(i & 1023);
  const int ch = (int)((i >> 10) & 511);
  const int b  = (int)(i >> 19);
  const int p0 = pq * 4;
  const size_t idx = (size_t)b * 2097152 + (size_t)(p0 >> 5) * 16384
                   + (size_t)((p0 >> 3) & 3) * 4096 + ch * 8 + (p0 & 7);
  *(half4v*)(outv + idx) = h;
}

// ---------------- Projection (split-bf16, ~fp32 accurate), fp16 out ----------------
// Q: natural [b][p][256].  K: chunk-major [b][ktile=128][32 chunks c=ch>>3][32 key][8 f16]
__global__ __launch_bounds__(512) void proj_kernel(
    const float* __restrict__ Xq, const float* __restrict__ Wq, const float* __restrict__ bq,
    const float* __restrict__ Xk, const float* __restrict__ Wk, const float* __restrict__ bk,
    _Float16* __restrict__ Qout, _Float16* __restrict__ Kout) {
  const int which = blockIdx.z;
  const float* __restrict__ X = which ? Xk : Xq;
  const float* __restrict__ W = which ? Wk : Wq;
  const float* __restrict__ bias = which ? bk : bq;
  _Float16* __restrict__ out = which ? Kout : Qout;

  const int b = blockIdx.y;
  const int p0 = blockIdx.x * 64;
  const int tid = threadIdx.x;
  const int w = tid >> 6, l = tid & 63;
  const int wp = w >> 2, wo = w & 3;
  const int lr = l & 15, lg = l >> 4;

  const float* __restrict__ Xb = X + (size_t)b * CIN * P_SZ;

  f4 acc[2][4];
  #pragma unroll
  for (int m = 0; m < 2; ++m)
    #pragma unroll
    for (int n = 0; n < 4; ++n) acc[m][n] = (f4){0.f, 0.f, 0.f, 0.f};

  const int prow0 = p0 + wp * 32 + lr;

  #pragma unroll 1
  for (int kc = 0; kc < CIN; kc += 32) {
    short8 ah[2], al[2];
    #pragma unroll
    for (int m = 0; m < 2; ++m) {
      const float* xp = Xb + (size_t)(kc + lg * 8) * P_SZ + (prow0 + m * 16);
      #pragma unroll
      for (int i = 0; i < 8; ++i) {
        float xv = xp[(size_t)i * P_SZ];
        unsigned short h = f2bf(xv);
        ah[m][i] = (short)h;
        al[m][i] = (short)f2bf(xv - bf2f(h));
      }
    }
    short8 bh[4], bl[4];
    #pragma unroll
    for (int n = 0; n < 4; ++n) {
      const float* wr = W + (size_t)(wo * 64 + n * 16 + lr) * CIN + kc + lg * 8;
      #pragma unroll
      for (int i = 0; i < 8; ++i) {
        float wv = wr[i];
        unsigned short h = f2bf(wv);
        bh[n][i] = (short)h;
        bl[n][i] = (short)f2bf(wv - bf2f(h));
      }
    }
    #pragma unroll
    for (int m = 0; m < 2; ++m)
      #pragma unroll
      for (int n = 0; n < 4; ++n) {
        acc[m][n] = __builtin_amdgcn_mfma_f32_16x16x32_bf16(ah[m], bh[n], acc[m][n], 0, 0, 0);
        acc[m][n] = __builtin_amdgcn_mfma_f32_16x16x32_bf16(ah[m], bl[n], acc[m][n], 0, 0, 0);
        acc[m][n] = __builtin_amdgcn_mfma_f32_16x16x32_bf16(al[m], bh[n], acc[m][n], 0, 0, 0);
      }
  }

  #pragma unroll
  for (int n = 0; n < 4; ++n) {
    const int o = wo * 64 + n * 16 + lr;
    const float bv = bias[o];
    #pragma unroll
    for (int m = 0; m < 2; ++m) {
      #pragma unroll
      for (int j = 0; j < 4; ++j) {
        const int p = p0 + wp * 32 + m * 16 + lg * 4 + j;
        const _Float16 val = (_Float16)(acc[m][n][j] + bv);
        if (which == 0) {
          out[((size_t)b * P_SZ + p) * CH + o] = val;
        } else {
          out[(size_t)b * 1048576 + (size_t)(p >> 5) * 8192
              + (size_t)(o >> 3) * 256 + (p & 31) * 8 + (o & 7)] = val;
        }
      }
    }
  }
}

// ---------------- Fused flash attention: swapped QK^T, in-register softmax ----------------
// 8 waves = 4 q-groups x 2 ch-halves. Wave (wq,half): 32 q rows, 256 out channels.
// acc = 8 f16v (128 VGPR) + qf 64 VGPR -> fits 256-VGPR budget (2 waves/SIMD), no spill.
// QK^T duplicated within the pair (cheaper than LDS S-exchange). Softmax in-register.
// K/V chunk-major in LDS, 3-buffer 2-deep global_load_lds pipeline, 1 barrier/iter.
template <int NSEG, bool DIRECT>
__global__ __launch_bounds__(512, 2) void attn_kernel(
    const _Float16* __restrict__ Qg, const _Float16* __restrict__ Kt,
    const _Float16* __restrict__ Vt, float* __restrict__ Opart,
    float* __restrict__ Mp, float* __restrict__ Lp, float* __restrict__ Og) {
  __shared__ char K_l[3][16384];
  __shared__ char V_l[3][32768];

  constexpr int nt = (P_SZ / NSEG) / KVB;
  int b, qt, seg;
  if (NSEG == 2) {
    const int g = blockIdx.x & 7;          // 8 (b,seg) groups -> 8 XCDs
    b = g >> 1; seg = g & 1; qt = blockIdx.x >> 3;    // qt in 0..31
  } else {
    b = blockIdx.x & 3; seg = 0; qt = blockIdx.x >> 2; // qt in 0..31
  }

  const int tid = threadIdx.x;
  const int w = tid >> 6, l = tid & 63;
  const int hi = l >> 5, l31 = l & 31;
  const int wq = w >> 1, half = w & 1;

  const char* Kb = (const char*)Kt + (size_t)b * 2097152 + (size_t)seg * nt * 16384;
  const char* Vb = (const char*)Vt + (size_t)b * 4194304 + (size_t)seg * nt * 32768;

#define STAGE(BUF, T) do { \
    const char* ksrc = Kb + (size_t)(T) * 16384; \
    const char* vsrc = Vb + (size_t)(T) * 32768; \
    gload16(ksrc + tid * 16,         &K_l[BUF][w * 1024]); \
    gload16(ksrc + 8192 + tid * 16,  &K_l[BUF][8192 + w * 1024]); \
    gload16(vsrc + tid * 16,         &V_l[BUF][w * 1024]); \
    gload16(vsrc + 8192 + tid * 16,  &V_l[BUF][8192 + w * 1024]); \
    gload16(vsrc + 16384 + tid * 16, &V_l[BUF][16384 + w * 1024]); \
    gload16(vsrc + 24576 + tid * 16, &V_l[BUF][24576 + w * 1024]); \
  } while (0)

  // Q fragments: B-operand [q=lane&31][ch chunks], natural global layout
  half8 qf[16];
  {
    const char* qrow = (const char*)Qg +
        ((size_t)b * P_SZ + qt * 128 + wq * 32 + l31) * 512;
    #pragma unroll
    for (int m = 0; m < 16; ++m) qf[m] = *(const half8*)(qrow + m * 32 + hi * 16);
  }

  f16v acc[8];
  #pragma unroll
  for (int n = 0; n < 8; ++n)
    acc[n] = (f16v){0,0,0,0, 0,0,0,0, 0,0,0,0, 0,0,0,0};

  float m_run = -1e30f, lsum = 0.f;
  const int kread = hi * 512 + l31 * 16;                  // + m*1024
  const int vread = hi * 8192 + half * 4096 + l31 * 16;   // + n*512 (+16384 for kh 2/3)

  STAGE(0, 0); STAGE(1, 1);
  asm volatile("s_waitcnt vmcnt(6)" ::: "memory");
  asm volatile("s_barrier" ::: "memory");
  __builtin_amdgcn_sched_barrier(0);

  int bufc = 0;
  #pragma unroll 1
  for (int t = 0; t < nt; ++t) {
    // ---- swapped QK^T: S^T[key][q], duplicated across the ch-half pair ----
    const char* kb = &K_l[bufc][0] + kread;
    f16v s = (f16v){0,0,0,0, 0,0,0,0, 0,0,0,0, 0,0,0,0};
    __builtin_amdgcn_s_setprio(1);
    #pragma unroll
    for (int m = 0; m < 16; ++m) {
      half8 kf = *(const half8*)(kb + m * 1024);
      s = __builtin_amdgcn_mfma_f32_32x32x16_f16(kf, qf[m], s, 0, 0, 0);
    }
    __builtin_amdgcn_s_setprio(0);

    // ---- in-register online softmax over 32 keys (per q=l31) ----
    float x0 = fmaxf(s[0], s[8]),  x1 = fmaxf(s[1], s[9]);
    float x2 = fmaxf(s[2], s[10]), x3 = fmaxf(s[3], s[11]);
    float x4 = fmaxf(s[4], s[12]), x5 = fmaxf(s[5], s[13]);
    float x6 = fmaxf(s[6], s[14]), x7 = fmaxf(s[7], s[15]);
    x0 = fmaxf(x0, x4); x1 = fmaxf(x1, x5); x2 = fmaxf(x2, x6); x3 = fmaxf(x3, x7);
    float pm = fmaxf(fmaxf(x0, x1), fmaxf(x2, x3));
    pm = fmaxf(pm, __shfl_xor(pm, 32));
    if (__any(pm > m_run + 10.f)) {          // rare rescale (defer-max, T13)
      const float mnew = fmaxf(m_run, pm);
      const float al = __expf(m_run - mnew);
      const int alb = __float_as_int(al);
      #pragma unroll
      for (int r = 0; r < 16; ++r) {
        const int cr = (r & 3) + 8 * (r >> 2);
        const float ar = __int_as_float(
            __builtin_amdgcn_ds_bpermute(cr * 4 + hi * 16, alb));
        #pragma unroll
        for (int n = 0; n < 8; ++n) acc[n][r] *= ar;
      }
      lsum *= al;
      m_run = mnew;
    }
    float p[16], psum;
    #pragma unroll
    for (int r = 0; r < 16; ++r) p[r] = __expf(s[r] - m_run);
    {
      float a0 = (p[0] + p[1]) + (p[2] + p[3]);
      float a1 = (p[4] + p[5]) + (p[6] + p[7]);
      float a2 = (p[8] + p[9]) + (p[10] + p[11]);
      float a3 = (p[12] + p[13]) + (p[14] + p[15]);
      psum = (a0 + a1) + (a2 + a3);
      psum += __shfl_xor(psum, 32);
    }
    lsum += psum;

    // ---- P -> fp16 A-fragments ----
    // lane(l31,hi) holds keys: c0:(0,1)+4hi c1:(2,3)+4hi c2:(8,9)+4hi c3:(10,11)+4hi
    // c4:(16,17)+4hi c5:(18,19)+4hi c6:(24,25)+4hi c7:(26,27)+4hi.
    // pa0 = keys [8hi..8hi+7], pa1 = keys [16+8hi..23+8hi]; cross-half copy via
    // shfl_xor(32), select by DESTINATION half.
    const int c0 = __builtin_bit_cast(int, __builtin_amdgcn_cvt_pkrtz(p[0], p[1]));
    const int c1 = __builtin_bit_cast(int, __builtin_amdgcn_cvt_pkrtz(p[2], p[3]));
    const int c2 = __builtin_bit_cast(int, __builtin_amdgcn_cvt_pkrtz(p[4], p[5]));
    const int c3 = __builtin_bit_cast(int, __builtin_amdgcn_cvt_pkrtz(p[6], p[7]));
    const int c4 = __builtin_bit_cast(int, __builtin_amdgcn_cvt_pkrtz(p[8], p[9]));
    const int c5 = __builtin_bit_cast(int, __builtin_amdgcn_cvt_pkrtz(p[10], p[11]));
    const int c6 = __builtin_bit_cast(int, __builtin_amdgcn_cvt_pkrtz(p[12], p[13]));
    const int c7 = __builtin_bit_cast(int, __builtin_amdgcn_cvt_pkrtz(p[14], p[15]));
    const int c0x = __shfl_xor(c0, 32), c1x = __shfl_xor(c1, 32);
    const int c2x = __shfl_xor(c2, 32), c3x = __shfl_xor(c3, 32);
    const int c4x = __shfl_xor(c4, 32), c5x = __shfl_xor(c5, 32);
    const int c6x = __shfl_xor(c6, 32), c7x = __shfl_xor(c7, 32);
    i4 w0v, w1v;
    w0v[0] = hi ? c2x : c0;  w0v[1] = hi ? c3x : c1;
    w0v[2] = hi ? c2  : c0x; w0v[3] = hi ? c3  : c1x;
    w1v[0] = hi ? c6x : c4;  w1v[1] = hi ? c7x : c5;
    w1v[2] = hi ? c6  : c4x; w1v[3] = hi ? c7  : c5x;
    const half8 pa0 = __builtin_bit_cast(half8, w0v);
    const half8 pa1 = __builtin_bit_cast(half8, w1v);

    // ---- issue stage t+2 (2-deep pipeline) ----
    const int bufs = bufc == 0 ? 2 : bufc - 1;   // (bufc+2)%3
    if (t + 2 < nt) STAGE(bufs, t + 2);

    // ---- PV: acc[q][ch-half] += P * V ----
    const char* vb = &V_l[bufc][0] + vread;
    __builtin_amdgcn_s_setprio(1);
    #pragma unroll
    for (int n = 0; n < 8; ++n) {
      half8 v0 = *(const half8*)(vb + n * 512);
      acc[n] = __builtin_amdgcn_mfma_f32_32x32x16_f16(pa0, v0, acc[n], 0, 0, 0);
      half8 v1 = *(const half8*)(vb + 16384 + n * 512);
      acc[n] = __builtin_amdgcn_mfma_f32_32x32x16_f16(pa1, v1, acc[n], 0, 0, 0);
    }
    __builtin_amdgcn_s_setprio(0);

    if (t + 2 < nt) { asm volatile("s_waitcnt vmcnt(6)" ::: "memory"); }
    else            { asm volatile("s_waitcnt vmcnt(0)" ::: "memory"); }
    asm volatile("s_barrier" ::: "memory");
    __builtin_amdgcn_sched_barrier(0);
    bufc = bufc == 2 ? 0 : bufc + 1;
  }
#undef STAGE

  const int qg0 = qt * 128 + wq * 32;
  if (!DIRECT) {
    float* Ob = Opart + (((size_t)seg * 4 + b) * P_SZ + qg0) * 512 + half * 256 + l31;
    #pragma unroll
    for (int n = 0; n < 8; ++n) {
      #pragma unroll
      for (int r = 0; r < 16; ++r) {
        const int q = (r & 3) + 8 * (r >> 2) + 4 * hi;
        Ob[(size_t)q * 512 + n * 32] = acc[n][r];
      }
    }
    if (half == 0 && l < 32) {
      const size_t mi = ((size_t)seg * 4 + b) * P_SZ + qg0 + l31;
      Mp[mi] = m_run; Lp[mi] = lsum;
    }
  } else {
    float linv[16];
    const int lb = __float_as_int(lsum);
    #pragma unroll
    for (int r = 0; r < 16; ++r) {
      const int cr = (r & 3) + 8 * (r >> 2);
      const float lq = __int_as_float(__builtin_amdgcn_ds_bpermute(cr * 4 + hi * 16, lb));
      linv[r] = 1.f / lq;
    }
    #pragma unroll
    for (int n = 0; n < 8; ++n) {
      #pragma unroll
      for (int r = 0; r < 16; ++r) {
        const int q = (r & 3) + 8 * (r >> 2) + 4 * hi;
        Og[((size_t)b * CV + half * 256 + n * 32 + l31) * P_SZ + qg0 + q] =
            acc[n][r] * linv[r];
      }
    }
  }
}

// ---------------- Combine: merge kv-segments, normalize, transpose [q][ch]->[ch][q] ----
template <int NSEG>
__global__ __launch_bounds__(256) void combine_kernel(
    const float* __restrict__ Opart, const float* __restrict__ Mp,
    const float* __restrict__ Lp, float* __restrict__ Og) {
  __shared__ float T[64][65];
  const int bx = blockIdx.x;
  const int ct = bx & 7, qt = (bx >> 3) & 63, b = bx >> 9;
  const int tid = threadIdx.x;
  {
    const int qi = tid >> 2, cj = tid & 3;
    const int q = qt * 64 + qi;
    const size_t mibase = (size_t)b * P_SZ + q;
    float M = -1e30f;
    #pragma unroll
    for (int s = 0; s < NSEG; ++s) M = fmaxf(M, Mp[(size_t)s * 4 * P_SZ + mibase]);
    float L = 0.f;
    f4 o0 = {0,0,0,0}, o1 = {0,0,0,0}, o2 = {0,0,0,0}, o3 = {0,0,0,0};
    #pragma unroll
    for (int s = 0; s < NSEG; ++s) {
      const float wgt = __expf(Mp[(size_t)s * 4 * P_SZ + mibase] - M);
      L += wgt * Lp[(size_t)s * 4 * P_SZ + mibase];
      const float* src = Opart + (((size_t)s * 4 + b) * P_SZ + q) * 512 + ct * 64 + cj * 16;
      o0 += wgt * ((const f4*)src)[0];
      o1 += wgt * ((const f4*)src)[1];
      o2 += wgt * ((const f4*)src)[2];
      o3 += wgt * ((const f4*)src)[3];
    }
    const float inv = 1.f / L;
    #pragma unroll
    for (int e = 0; e < 4; ++e) {
      T[qi][cj * 16 + e]      = o0[e] * inv;
      T[qi][cj * 16 + 4 + e]  = o1[e] * inv;
      T[qi][cj * 16 + 8 + e]  = o2[e] * inv;
      T[qi][cj * 16 + 12 + e] = o3[e] * inv;
    }
  }
  __syncthreads();
  const int ci = tid >> 2, qj = tid & 3;
  #pragma unroll
  for (int i = 0; i < 4; ++i) {
    f4 v;
    #pragma unroll
    for (int e = 0; e < 4; ++e) v[e] = T[qj * 16 + i * 4 + e][ci];
    *(f4*)&Og[((size_t)b * CV + ct * 64 + ci) * P_SZ + qt * 64 + qj * 16 + i * 4] = v;
  }
}

extern "C" void kernel_launch(void* const* d_in, const int* in_sizes, int n_in,
                              void* d_out, int out_size, void* d_ws, size_t ws_size,
                              hipStream_t stream) {
  const float* x  = (const float*)d_in[0];
  const float* f  = (const float*)d_in[1];
  const float* Wq = (const float*)d_in[2];
  const float* bq = (const float*)d_in[3];
  const float* Wk = (const float*)d_in[4];
  const float* bk = (const float*)d_in[5];
  float* out = (float*)d_out;

  char* ws = (char*)d_ws;
  _Float16* Qf = (_Float16*)ws;                                   // 8 MB natural
  _Float16* Kf = (_Float16*)(ws + ((size_t)8 << 20));             // 8 MB chunk-tiled
  _Float16* Vf = (_Float16*)(ws + ((size_t)16 << 20));            // 16 MB chunk-tiled
  float* Mp    = (float*)(ws + ((size_t)32 << 20));               // <=128 KB
  float* Lp    = (float*)(ws + ((size_t)32 << 20) + 262144);      // <=128 KB
  float* Opart = (float*)(ws + ((size_t)33 << 20));               // nseg*32 MB

  vconv_kernel<<<dim3(8192), dim3(256), 0, stream>>>(f, Vf);
  proj_kernel<<<dim3(64, 4, 2), dim3(512), 0, stream>>>(x, Wq, bq, f, Wk, bk, Qf, Kf);

  const size_t need2 = ((size_t)33 << 20) + ((size_t)64 << 20);
  const size_t need1 = ((size_t)33 << 20) + ((size_t)32 << 20);
  if (ws_size >= need2) {
    attn_kernel<2, false><<<dim3(256), dim3(512), 0, stream>>>(Qf, Kf, Vf, Opart, Mp, Lp, nullptr);
    combine_kernel<2><<<dim3(2048), dim3(256), 0, stream>>>(Opart, Mp, Lp, out);
  } else if (ws_size >= need1) {
    attn_kernel<1, false><<<dim3(128), dim3(512), 0, stream>>>(Qf, Kf, Vf, Opart, Mp, Lp, nullptr);
    combine_kernel<1><<<dim3(2048), dim3(256), 0, stream>>>(Opart, Mp, Lp, out);
  } else {
    attn_kernel<1, true><<<dim3(128), dim3(512), 0, stream>>>(Qf, Kf, Vf, nullptr, nullptr, nullptr, out);
  }
}